// Round 8
// baseline (312.778 us; speedup 1.0000x reference)
//
#include <hip/hip_runtime.h>
#include <hip/hip_fp16.h>

typedef _Float16 half8 __attribute__((ext_vector_type(8)));
typedef _Float16 half2v __attribute__((ext_vector_type(2)));
typedef float floatx4 __attribute__((ext_vector_type(4)));

#if __has_builtin(__builtin_amdgcn_fdot2)
#define FDOT2(a, b, c) __builtin_amdgcn_fdot2((a), (b), (c), false)
#else
#define FDOT2(a, b, c) ((float)(a)[0] * (float)(b)[0] + (float)(a)[1] * (float)(b)[1] + (c))
#endif

// ---------------- prepack: hid Bfrag + bias48 + conv_in Bfrags --------------
__global__ void k_prepack_small(const float* __restrict__ WhW, const float* __restrict__ Whb,
                                const float* __restrict__ WinW, const float* __restrict__ PcW,
                                const int* __restrict__ dom,
                                __half* __restrict__ Bpack, float* __restrict__ bias48,
                                __half* __restrict__ B36, __half* __restrict__ B12) {
  const int tid = threadIdx.x;
  const int dm = dom[0];
  for (int i = tid; i < 11 * 3 * 64 * 8; i += 256) {
    const int j = i & 7, lane = (i >> 3) & 63, nt = (i >> 9) % 3, s = i / 1536;
    const int n = lane & 15, q = lane >> 4;
    const int k = q * 8 + j;
    const int oc = nt * 16 + n;
    int tap, ch; bool valid = true;
    if (s < 9)       { tap = s;      ch = k; }
    else if (s == 9) { tap = k >> 2; ch = 32 + (k & 3); }
    else             { tap = 8;      ch = 32 + k; valid = (k < 4); }
    float v = 0.f;
    if (valid && oc < 36 && ch < 36) v = WhW[(oc * 36 + ch) * 9 + tap];
    Bpack[i] = __float2half(v);
  }
  if (tid < 48) bias48[tid] = (tid < 36) ? Whb[tid] : 0.f;
  for (int i = tid; i < 3072 + 1024; i += 256) {
    const bool is36 = i < 3072;
    const int ii = is36 ? i : i - 3072;
    const int NT = is36 ? 3 : 1, OCv = is36 ? 36 : 12;
    const int j = ii & 7, lane = (ii >> 3) & 63;
    const int nt = (ii >> 9) % NT, s = ii / (NT * 512);
    const int n = lane & 15, q = lane >> 4, oc = nt * 16 + n;
    int ky, kx, c; bool valid = (oc < OCv);
    if (s == 0) { const int pi = q * 2 + (j >> 2); ky = pi / 3; kx = pi % 3; c = j & 3; }
    else        { ky = 2; kx = 2; c = j; valid = valid && (q == 0 && j < 4); }
    valid = valid && (c < 3);
    float v = 0.f;
    if (valid) {
      const float* W = is36 ? WinW : (PcW + (size_t)dm * 12 * 27);
      v = W[((oc * 3 + c) * 3 + ky) * 3 + kx];
    }
    (is36 ? B36 : B12)[ii] = __float2half(v);
  }
}

// ---------------- prepack: plain f16 FC weights in activation-storage order -
__global__ void k_prepack_fcp(const float* __restrict__ PlW, const int* __restrict__ dom,
                              const float* __restrict__ WfcW,
                              __half* __restrict__ Wpp, __half* __restrict__ Wshp) {
  const int dm = dom[0];
  const int gid = blockIdx.x * 256 + threadIdx.x;
  const int stride = gridDim.x * 256;
  for (int i = gid; i < 147456; i += stride) {
    const int hid = i / 12288, k = i - hid * 12288;
    const int oc = k % 12, pix = k / 12;
    Wpp[i] = __float2half(PlW[((size_t)dm * 12 + hid) * 12288 + oc * 1024 + pix]);
  }
  for (int i = gid; i < 27648; i += stride) {
    const int hid = i / 2304, k = i - hid * 2304;
    const int oc = k % 36, p = k / 36;
    Wshp[i] = __float2half(WfcW[hid * 2304 + oc * 64 + p]);
  }
}

// ---------------- fused private branch: conv(3->12,leaky)+pool + FC ---------
// 512 threads (8 waves), fdot2-based FC (thread = 2 pixels = 12 half2).
__global__ __launch_bounds__(512)
void k_priv(const float* __restrict__ xin, const __half* __restrict__ B12,
            const float* __restrict__ Pcb, const int* __restrict__ dom,
            const __half* __restrict__ Wpp, const float* __restrict__ Plb,
            float* __restrict__ pb) {
  __shared__ __align__(16) __half img[66 * 68 * 4];
  __shared__ __align__(16) __half ptile[1024 * 12];
  __shared__ float red[8][12];
  const int tid = threadIdx.x, b = blockIdx.x;
  const int lane = tid & 63, wave = tid >> 6, ln = lane & 15, q = lane >> 4;
  const int dm = dom[0];

  float c0[8], c1[8], c2[8];
#pragma unroll
  for (int u = 0; u < 8; ++u) {
    const int i = tid + u * 512;
    const int y = i >> 6, px = i & 63;
    const float* p0 = xin + (size_t)b * 12288 + y * 64 + px;
    c0[u] = p0[0]; c1[u] = p0[4096]; c2[u] = p0[8192];
  }
  const half8 Bf0 = *(const half8*)(B12 + lane * 8);
  const half8 Bf1 = *(const half8*)(B12 + (64 + lane) * 8);
  const float bv = (ln < 12) ? Pcb[dm * 12 + ln] : 0.f;
  for (int i = tid; i < 264; i += 512) {
    int hidx;
    if (i < 136) { const int r = (i < 68) ? 0 : 65; hidx = (r * 68 + (i % 68)) * 4; }
    else { const int j = i - 136; const int r = 1 + (j & 63); hidx = (r * 68 + ((j < 64) ? 0 : 65)) * 4; }
    *(unsigned long long*)&img[hidx] = 0ULL;
  }
#pragma unroll
  for (int u = 0; u < 8; ++u) {
    const int i = tid + u * 512;
    const int y = i >> 6, px = i & 63;
    __half2 lo = __floats2half2_rn(c0[u], c1[u]);
    __half2 hi = __floats2half2_rn(c2[u], 0.f);
    *(uint2*)&img[((y + 1) * 68 + px + 1) * 4] =
        make_uint2(*(unsigned int*)&lo, *(unsigned int*)&hi);
  }
  __syncthreads();

  const int dy0_t[4] = {-1, -1, 0, 1}, dx0_t[4] = {-1, 1, 0, -1};
  const int dy1_t[4] = {-1, 0, 0, 1},  dx1_t[4] = {0, -1, 1, 0};
  const int dy0 = dy0_t[q], dx0 = dx0_t[q], dy1 = dy1_t[q], dx1 = dx1_t[q];
  const int zoff = (65 * 68 + 66) * 4;

#pragma unroll 1
  for (int kk = 0; kk < 4; ++kk) {
    const int pr = 8 * kk + wave;
    floatx4 acc[2][4];
#pragma unroll
    for (int rb = 0; rb < 2; ++rb)
#pragma unroll
      for (int t = 0; t < 4; ++t) acc[rb][t] = (floatx4){0.f, 0.f, 0.f, 0.f};
#pragma unroll
    for (int rb = 0; rb < 2; ++rb) {
      const int yl = 2 * pr + rb + 1;
#pragma unroll
      for (int t = 0; t < 4; ++t) {
        const int xc = t * 16 + ln + 1;
        union { half8 h; uint2 u[2]; } A;
        A.u[0] = *(const uint2*)&img[((yl + dy0) * 68 + xc + dx0) * 4];
        A.u[1] = *(const uint2*)&img[((yl + dy1) * 68 + xc + dx1) * 4];
        acc[rb][t] = __builtin_amdgcn_mfma_f32_16x16x32_f16(A.h, Bf0, acc[rb][t], 0, 0, 0);
        union { half8 h; uint2 u[2]; } A1;
        A1.u[0] = *(const uint2*)&img[(q == 0) ? ((yl + 1) * 68 + xc + 1) * 4 : zoff];
        A1.u[1] = make_uint2(0u, 0u);
        acc[rb][t] = __builtin_amdgcn_mfma_f32_16x16x32_f16(A1.h, Bf1, acc[rb][t], 0, 0, 0);
      }
    }
    if (ln < 12) {
#pragma unroll
      for (int t = 0; t < 4; ++t) {
        const floatx4 ca = acc[0][t], cb = acc[1][t];
        float v0 = fmaxf(fmaxf(ca.x, ca.y), fmaxf(cb.x, cb.y)) + bv;
        float v1 = fmaxf(fmaxf(ca.z, ca.w), fmaxf(cb.z, cb.w)) + bv;
        v0 = (v0 > 0.f) ? v0 : 0.001f * v0;
        v1 = (v1 > 0.f) ? v1 : 0.001f * v1;
        const int px = t * 8 + q * 2;
        ptile[(pr * 32 + px) * 12 + ln]     = __float2half(v0);
        ptile[(pr * 32 + px + 1) * 12 + ln] = __float2half(v1);
      }
    }
  }
  __syncthreads();

  // FC via fdot2: thread = 2 pixels (24 halves = 12 half2)
  half2v a2[12];
  {
    const half2v* pt2 = (const half2v*)ptile;
#pragma unroll
    for (int j = 0; j < 12; ++j) a2[j] = pt2[tid * 12 + j];
  }
  float s[12];
#pragma unroll 1
  for (int hp = 0; hp < 6; ++hp) {
    const half2v* w0 = (const half2v*)(Wpp + (size_t)(2 * hp) * 12288) + tid * 12;
    const half2v* w1 = w0 + 6144;
    half2v wv0[12], wv1[12];
#pragma unroll
    for (int j = 0; j < 12; ++j) { wv0[j] = w0[j]; wv1[j] = w1[j]; }
    float s0 = 0.f, s1 = 0.f;
#pragma unroll
    for (int j = 0; j < 12; ++j) {
      s0 = FDOT2(a2[j], wv0[j], s0);
      s1 = FDOT2(a2[j], wv1[j], s1);
    }
    s[2 * hp] = s0; s[2 * hp + 1] = s1;
  }
#pragma unroll
  for (int i = 0; i < 12; ++i)
    for (int off = 32; off > 0; off >>= 1) s[i] += __shfl_down(s[i], off, 64);
  if (lane == 0)
#pragma unroll
    for (int i = 0; i < 12; ++i) red[wave][i] = s[i];
  __syncthreads();
  if (tid < 12) {
    float acc = Plb[dm * 12 + tid];
#pragma unroll
    for (int w = 0; w < 8; ++w) acc += red[w][tid];
    pb[b * 12 + tid] = acc;
  }
}

// ---------------- fused shared tower: conv1+conv2+conv3+fc, 1024 threads ----
// 16 waves = 4 waves/SIMD at 1 block/CU.
__global__ __launch_bounds__(1024)
void k_tower(const float* __restrict__ xin, const __half* __restrict__ B36,
             const float* __restrict__ Winb, const __half* __restrict__ Bp,
             const float* __restrict__ b48g, const __half* __restrict__ Wshp,
             const float* __restrict__ Wfcb, float* __restrict__ hb) {
  extern __shared__ __align__(16) char ldsx[];
  __half* uA  = (__half*)ldsx;                 // img [66][68][4] / hid Bpack
  __half* A1h = (__half*)(ldsx + 35904);       // conv1-out records [34][34][40h] / fcstage
  __half* O2h = (__half*)(ldsx + 128384);      // conv2-out records [18][18][40h]
  float*  red = (float*)(ldsx + 154304);       // [4][12]
  const int tid = threadIdx.x, b = blockIdx.x;
  const int lane = tid & 63, wave = tid >> 6, ln = lane & 15, q = lane >> 4;

  // ---- T1: stage image + zero all halos ----
  float c0[4], c1[4], c2[4];
#pragma unroll
  for (int u = 0; u < 4; ++u) {
    const int i = tid + u * 1024;
    const int y = i >> 6, px = i & 63;
    const float* p0 = xin + (size_t)b * 12288 + y * 64 + px;
    c0[u] = p0[0]; c1[u] = p0[4096]; c2[u] = p0[8192];
  }
  half8 Bf[2][3];
#pragma unroll
  for (int s = 0; s < 2; ++s)
#pragma unroll
    for (int nt = 0; nt < 3; ++nt)
      Bf[s][nt] = *(const half8*)(B36 + ((s * 3 + nt) * 64 + lane) * 8);
  float bv36[3];
#pragma unroll
  for (int nt = 0; nt < 3; ++nt) {
    const int oc = nt * 16 + ln;
    bv36[nt] = (oc < 36) ? Winb[oc] : 0.f;
  }
  for (int i = tid; i < 264; i += 1024) {
    int hidx;
    if (i < 136) { const int r = (i < 68) ? 0 : 65; hidx = (r * 68 + (i % 68)) * 4; }
    else { const int j = i - 136; const int r = 1 + (j & 63); hidx = (r * 68 + ((j < 64) ? 0 : 65)) * 4; }
    *(unsigned long long*)&uA[hidx] = 0ULL;
  }
  for (int u = tid; u < 1320; u += 1024) {
    const int rec = u / 10, part = u % 10;
    int r, c;
    if (rec < 34) { r = 0; c = rec; }
    else if (rec < 68) { r = 33; c = rec - 34; }
    else if (rec < 100) { r = rec - 68 + 1; c = 0; }
    else { r = rec - 100 + 1; c = 33; }
    *(unsigned long long*)&A1h[(r * 34 + c) * 40 + part * 4] = 0ULL;
  }
  for (int u = tid; u < 680; u += 1024) {
    const int rec = u / 10, part = u % 10;
    int r, c;
    if (rec < 18) { r = 0; c = rec; }
    else if (rec < 36) { r = 17; c = rec - 18; }
    else if (rec < 52) { r = rec - 36 + 1; c = 0; }
    else { r = rec - 52 + 1; c = 17; }
    *(unsigned long long*)&O2h[(r * 18 + c) * 40 + part * 4] = 0ULL;
  }
#pragma unroll
  for (int u = 0; u < 4; ++u) {
    const int i = tid + u * 1024;
    const int y = i >> 6, px = i & 63;
    __half2 lo = __floats2half2_rn(c0[u], c1[u]);
    __half2 hi = __floats2half2_rn(c2[u], 0.f);
    *(uint2*)&uA[((y + 1) * 68 + px + 1) * 4] =
        make_uint2(*(unsigned int*)&lo, *(unsigned int*)&hi);
  }
  __syncthreads();

  // ---- T2: conv1 + pool -> A1 records (16 waves x 2 pooled rows) ----
  {
    const int dy0_t[4] = {-1, -1, 0, 1}, dx0_t[4] = {-1, 1, 0, -1};
    const int dy1_t[4] = {-1, 0, 0, 1},  dx1_t[4] = {0, -1, 1, 0};
    const int dy0 = dy0_t[q], dx0 = dx0_t[q], dy1 = dy1_t[q], dx1 = dx1_t[q];
    const int zoff = (65 * 68 + 66) * 4;
#pragma unroll 1
    for (int kk = 0; kk < 2; ++kk) {
      const int pr = 16 * kk + wave;
      floatx4 acc[2][4][3];
#pragma unroll
      for (int rb = 0; rb < 2; ++rb)
#pragma unroll
        for (int t = 0; t < 4; ++t)
#pragma unroll
          for (int nt = 0; nt < 3; ++nt) acc[rb][t][nt] = (floatx4){0.f, 0.f, 0.f, 0.f};
#pragma unroll
      for (int rb = 0; rb < 2; ++rb) {
        const int yl = 2 * pr + rb + 1;
#pragma unroll
        for (int t = 0; t < 4; ++t) {
          const int xc = t * 16 + ln + 1;
          union { half8 h; uint2 u[2]; } A;
          A.u[0] = *(const uint2*)&uA[((yl + dy0) * 68 + xc + dx0) * 4];
          A.u[1] = *(const uint2*)&uA[((yl + dy1) * 68 + xc + dx1) * 4];
#pragma unroll
          for (int nt = 0; nt < 3; ++nt)
            acc[rb][t][nt] = __builtin_amdgcn_mfma_f32_16x16x32_f16(A.h, Bf[0][nt], acc[rb][t][nt], 0, 0, 0);
          union { half8 h; uint2 u[2]; } A1v;
          A1v.u[0] = *(const uint2*)&uA[(q == 0) ? ((yl + 1) * 68 + xc + 1) * 4 : zoff];
          A1v.u[1] = make_uint2(0u, 0u);
#pragma unroll
          for (int nt = 0; nt < 3; ++nt)
            acc[rb][t][nt] = __builtin_amdgcn_mfma_f32_16x16x32_f16(A1v.h, Bf[1][nt], acc[rb][t][nt], 0, 0, 0);
        }
      }
#pragma unroll
      for (int t = 0; t < 4; ++t)
#pragma unroll
        for (int nt = 0; nt < 3; ++nt) {
          const int oc = nt * 16 + ln;
          if (oc < 36) {
            const floatx4 ca = acc[0][t][nt], cb = acc[1][t][nt];
            const float v0 = fmaxf(fmaxf(fmaxf(ca.x, ca.y), fmaxf(cb.x, cb.y)) + bv36[nt], 0.f);
            const float v1 = fmaxf(fmaxf(fmaxf(ca.z, ca.w), fmaxf(cb.z, cb.w)) + bv36[nt], 0.f);
            const int px = t * 8 + q * 2;
            A1h[((pr + 1) * 34 + px + 1) * 40 + oc] = __float2half(v0);
            A1h[((pr + 1) * 34 + px + 2) * 40 + oc] = __float2half(v1);
          }
        }
    }
  }
  __syncthreads();

  // ---- T3: load hid Bpack into uA (img dead) ----
  {
    uint4 bpr[3];
#pragma unroll
    for (int u = 0; u < 3; ++u) {
      const int i = tid + u * 1024;
      bpr[u] = (i < 2112) ? ((const uint4*)Bp)[i] : make_uint4(0, 0, 0, 0);
    }
#pragma unroll
    for (int u = 0; u < 3; ++u) {
      const int i = tid + u * 1024;
      if (i < 2112) ((uint4*)uA)[i] = bpr[u];
    }
  }
  float bb[3];
#pragma unroll
  for (int nt = 0; nt < 3; ++nt) bb[nt] = b48g[nt * 16 + ln];
  __syncthreads();

  const __half* lB = uA + lane * 8;
  const int tA = 2 * q, tB = 2 * q + 1;

  // ---- T4: conv2 + pool -> O2 records (16 waves x 1 pooled row) ----
  {
    const int roA = ((tA / 3) * 34 + (tA % 3)) * 40 + 32;
    const int roB = ((tB / 3) * 34 + (tB % 3)) * 40 + 32;
    const int roC = (2 * 34 + 2) * 40 + 32;
    const int r0 = 2 * wave;
    int baseA[4];
#pragma unroll
    for (int mt = 0; mt < 4; ++mt)
      baseA[mt] = ((r0 + (mt >> 1)) * 34 + (mt & 1) * 16 + ln) * 40 + q * 8;
    floatx4 acc[4][3];
#pragma unroll
    for (int mt = 0; mt < 4; ++mt)
#pragma unroll
      for (int nt = 0; nt < 3; ++nt) acc[mt][nt] = (floatx4){0.f, 0.f, 0.f, 0.f};
#pragma unroll
    for (int s = 0; s < 9; ++s) {
      const int ky = s / 3, kx = s % 3;
      const half8 B0 = *(const half8*)&lB[(s * 3 + 0) * 512];
      const half8 B1 = *(const half8*)&lB[(s * 3 + 1) * 512];
      const half8 B2 = *(const half8*)&lB[(s * 3 + 2) * 512];
#pragma unroll
      for (int mt = 0; mt < 4; ++mt) {
        const half8 A = *(const half8*)&A1h[baseA[mt] + (ky * 34 + kx) * 40];
        acc[mt][0] = __builtin_amdgcn_mfma_f32_16x16x32_f16(A, B0, acc[mt][0], 0, 0, 0);
        acc[mt][1] = __builtin_amdgcn_mfma_f32_16x16x32_f16(A, B1, acc[mt][1], 0, 0, 0);
        acc[mt][2] = __builtin_amdgcn_mfma_f32_16x16x32_f16(A, B2, acc[mt][2], 0, 0, 0);
      }
    }
#pragma unroll
    for (int s = 9; s <= 10; ++s) {
      const half8 B0 = *(const half8*)&lB[(s * 3 + 0) * 512];
      const half8 B1 = *(const half8*)&lB[(s * 3 + 1) * 512];
      const half8 B2 = *(const half8*)&lB[(s * 3 + 2) * 512];
      const int oA = (s == 9) ? roA : roC, oB = (s == 9) ? roB : roC;
#pragma unroll
      for (int mt = 0; mt < 4; ++mt) {
        union { half8 h; uint2 u[2]; } au;
        au.u[0] = *(const uint2*)&A1h[baseA[mt] + oA];
        au.u[1] = *(const uint2*)&A1h[baseA[mt] + oB];
        acc[mt][0] = __builtin_amdgcn_mfma_f32_16x16x32_f16(au.h, B0, acc[mt][0], 0, 0, 0);
        acc[mt][1] = __builtin_amdgcn_mfma_f32_16x16x32_f16(au.h, B1, acc[mt][1], 0, 0, 0);
        acc[mt][2] = __builtin_amdgcn_mfma_f32_16x16x32_f16(au.h, B2, acc[mt][2], 0, 0, 0);
      }
    }
    const int py = wave;
#pragma unroll
    for (int h = 0; h < 2; ++h)
#pragma unroll
      for (int nt = 0; nt < 3; ++nt) {
        const int oc = nt * 16 + ln;
        if (oc < 36) {
          const floatx4 ca = acc[h][nt], cb = acc[2 + h][nt];
          const float v0 = fmaxf(fmaxf(fmaxf(ca.x, ca.y), fmaxf(cb.x, cb.y)) + bb[nt], 0.f);
          const float v1 = fmaxf(fmaxf(fmaxf(ca.z, ca.w), fmaxf(cb.z, cb.w)) + bb[nt], 0.f);
          const int px = h * 8 + q * 2;
          O2h[((py + 1) * 18 + px + 1) * 40 + oc] = __float2half(v0);
          O2h[((py + 1) * 18 + px + 2) * 40 + oc] = __float2half(v1);
        }
      }
  }
  __syncthreads();

  // ---- T5: conv3 + pool -> fcstage (waves 0..7, 2 m-tiles each) ----
  if (wave < 8) {
    const int roA = ((tA / 3) * 18 + (tA % 3)) * 40 + 32;
    const int roB = ((tB / 3) * 18 + (tB % 3)) * 40 + 32;
    const int roC = (2 * 18 + 2) * 40 + 32;
    int baseA[2];
#pragma unroll
    for (int mt = 0; mt < 2; ++mt)
      baseA[mt] = ((2 * wave + mt) * 18 + ln) * 40 + q * 8;
    floatx4 acc[2][3];
#pragma unroll
    for (int mt = 0; mt < 2; ++mt)
#pragma unroll
      for (int nt = 0; nt < 3; ++nt) acc[mt][nt] = (floatx4){0.f, 0.f, 0.f, 0.f};
#pragma unroll
    for (int s = 0; s < 9; ++s) {
      const int ky = s / 3, kx = s % 3;
      const half8 B0 = *(const half8*)&lB[(s * 3 + 0) * 512];
      const half8 B1 = *(const half8*)&lB[(s * 3 + 1) * 512];
      const half8 B2 = *(const half8*)&lB[(s * 3 + 2) * 512];
#pragma unroll
      for (int mt = 0; mt < 2; ++mt) {
        const half8 A = *(const half8*)&O2h[baseA[mt] + (ky * 18 + kx) * 40];
        acc[mt][0] = __builtin_amdgcn_mfma_f32_16x16x32_f16(A, B0, acc[mt][0], 0, 0, 0);
        acc[mt][1] = __builtin_amdgcn_mfma_f32_16x16x32_f16(A, B1, acc[mt][1], 0, 0, 0);
        acc[mt][2] = __builtin_amdgcn_mfma_f32_16x16x32_f16(A, B2, acc[mt][2], 0, 0, 0);
      }
    }
#pragma unroll
    for (int s = 9; s <= 10; ++s) {
      const half8 B0 = *(const half8*)&lB[(s * 3 + 0) * 512];
      const half8 B1 = *(const half8*)&lB[(s * 3 + 1) * 512];
      const half8 B2 = *(const half8*)&lB[(s * 3 + 2) * 512];
      const int oA = (s == 9) ? roA : roC, oB = (s == 9) ? roB : roC;
#pragma unroll
      for (int mt = 0; mt < 2; ++mt) {
        union { half8 h; uint2 u[2]; } au;
        au.u[0] = *(const uint2*)&O2h[baseA[mt] + oA];
        au.u[1] = *(const uint2*)&O2h[baseA[mt] + oB];
        acc[mt][0] = __builtin_amdgcn_mfma_f32_16x16x32_f16(au.h, B0, acc[mt][0], 0, 0, 0);
        acc[mt][1] = __builtin_amdgcn_mfma_f32_16x16x32_f16(au.h, B1, acc[mt][1], 0, 0, 0);
        acc[mt][2] = __builtin_amdgcn_mfma_f32_16x16x32_f16(au.h, B2, acc[mt][2], 0, 0, 0);
      }
    }
#pragma unroll
    for (int nt = 0; nt < 3; ++nt) {
      const int oc = nt * 16 + ln;
      if (oc < 36) {
        const floatx4 ca = acc[0][nt], cb = acc[1][nt];
        const float v0 = fmaxf(fmaxf(fmaxf(ca.x, ca.y), fmaxf(cb.x, cb.y)) + bb[nt], 0.f);
        const float v1 = fmaxf(fmaxf(fmaxf(ca.z, ca.w), fmaxf(cb.z, cb.w)) + bb[nt], 0.f);
        const int px = q * 2;
        A1h[(wave * 8 + px) * 36 + oc]     = __float2half(v0);
        A1h[(wave * 8 + px + 1) * 36 + oc] = __float2half(v1);
      }
    }
  }
  __syncthreads();

  // ---- T6: shared FC [2304]->[12] + relu (first 4 waves) ----
  if (tid < 256) {
    const int px_lin = tid >> 2, part = tid & 3;
    const int k0 = px_lin * 36 + part * 9;
    float af[9];
#pragma unroll
    for (int j = 0; j < 9; ++j) af[j] = __half2float(A1h[k0 + j]);
    float s[12];
#pragma unroll
    for (int hid = 0; hid < 12; ++hid) {
      const __half* w = Wshp + hid * 2304 + k0;
      float acc = 0.f;
#pragma unroll
      for (int j = 0; j < 9; ++j) acc = fmaf(af[j], __half2float(w[j]), acc);
      s[hid] = acc;
    }
#pragma unroll
    for (int i = 0; i < 12; ++i)
      for (int off = 32; off > 0; off >>= 1) s[i] += __shfl_down(s[i], off, 64);
    if (lane == 0)
#pragma unroll
      for (int i = 0; i < 12; ++i) red[wave * 12 + i] = s[i];
  }
  __syncthreads();
  if (tid < 12)
    hb[b * 12 + tid] = fmaxf(red[tid] + red[12 + tid] + red[24 + tid] + red[36 + tid] + Wfcb[tid], 0.f);
}

// ---------------- per-sample MoE heads --------------------------------------
__global__ __launch_bounds__(256)
void k_heads(const float* __restrict__ h, const float* __restrict__ p,
             const int* __restrict__ tt,
             const float* __restrict__ W1, const float* __restrict__ b1,
             const float* __restrict__ W2, const float* __restrict__ b2,
             const float* __restrict__ W3, const float* __restrict__ b3,
             float* __restrict__ out) {
  const int b = blockIdx.x * 256 + threadIdx.x;
  if (b >= 1024) return;
  const int t = tt[b];
  float xv[24];
#pragma unroll
  for (int i = 0; i < 12; ++i) xv[i] = h[b * 12 + i];
#pragma unroll
  for (int i = 0; i < 12; ++i) xv[12 + i] = p[b * 12 + i];
  float h1[28];
  const float* w1 = W1 + t * 28 * 24;
#pragma unroll 1
  for (int i = 0; i < 28; ++i) {
    float s = b1[t * 28 + i];
#pragma unroll
    for (int j = 0; j < 24; ++j) s = fmaf(w1[i * 24 + j], xv[j], s);
    h1[i] = fmaxf(s, 0.f);
  }
  float h2[14];
  const float* w2 = W2 + t * 14 * 28;
#pragma unroll 1
  for (int i = 0; i < 14; ++i) {
    float s = b2[t * 14 + i];
#pragma unroll
    for (int j = 0; j < 28; ++j) s = fmaf(w2[i * 28 + j], h1[j], s);
    h2[i] = fmaxf(s, 0.f);
  }
  const float* w3 = W3 + t * 5 * 14;
#pragma unroll
  for (int i = 0; i < 5; ++i) {
    float s = b3[t * 5 + i];
#pragma unroll
    for (int j = 0; j < 14; ++j) s = fmaf(w3[i * 14 + j], h2[j], s);
    out[b * 5 + i] = s;
  }
}

extern "C" void kernel_launch(void* const* d_in, const int* in_sizes, int n_in,
                              void* d_out, int out_size, void* d_ws, size_t ws_size,
                              hipStream_t stream) {
  const float* x_s  = (const float*)d_in[0];
  const float* x_p  = (const float*)d_in[1];
  const int*   tt   = (const int*)d_in[2];
  const int*   dom  = (const int*)d_in[3];
  const float* WinW = (const float*)d_in[4];
  const float* Winb = (const float*)d_in[5];
  const float* WhW  = (const float*)d_in[6];
  const float* Whb  = (const float*)d_in[7];
  const float* WfcW = (const float*)d_in[8];
  const float* Wfcb = (const float*)d_in[9];
  const float* PcW  = (const float*)d_in[10];
  const float* Pcb  = (const float*)d_in[11];
  const float* PlW  = (const float*)d_in[12];
  const float* Plb  = (const float*)d_in[13];
  const float* H1W  = (const float*)d_in[14];
  const float* H1b  = (const float*)d_in[15];
  const float* H2W  = (const float*)d_in[16];
  const float* H2b  = (const float*)d_in[17];
  const float* H3W  = (const float*)d_in[18];
  const float* H3b  = (const float*)d_in[19];
  float* out = (float*)d_out;

  char* ws = (char*)d_ws;
  __half* Bp   = (__half*)(ws + 0);        // 33,792 B
  float*  b48  = (float*)(ws + 33792);     // 192
  __half* B36  = (__half*)(ws + 33984);    // 6,144
  __half* B12  = (__half*)(ws + 40128);    // 2,048
  __half* Wpp  = (__half*)(ws + 42176);    // [12][12288] f16
  __half* Wshp = (__half*)(ws + 337088);   // [12][2304]  f16
  float*  hb   = (float*)(ws + 392384);    // [1024][12]
  float*  pb   = (float*)(ws + 441536);    // [1024][12]

  k_prepack_small<<<1, 256, 0, stream>>>(WhW, Whb, WinW, PcW, dom, Bp, b48, B36, B12);
  k_prepack_fcp<<<96, 256, 0, stream>>>(PlW, dom, WfcW, Wpp, Wshp);
  k_priv<<<1024, 512, 0, stream>>>(x_p, B12, Pcb, dom, Wpp, Plb, pb);
  k_tower<<<1024, 1024, 154496, stream>>>(x_s, B36, Winb, Bp, b48, Wshp, Wfcb, hb);
  k_heads<<<4, 256, 0, stream>>>(hb, pb, tt, H1W, H1b, H2W, H2b, H3W, H3b, out);
}